// Round 3
// baseline (28727.499 us; speedup 1.0000x reference)
//
#include <hip/hip_runtime.h>
#include <stdint.h>

#define T_STEPS 2048
#define BATCH 32
#define EDIM 512
#define HDIM 512
#define NWG 32
#define NTHR 512

typedef __attribute__((ext_vector_type(8))) short bf16x8;
typedef __attribute__((ext_vector_type(4))) float f32x4;
typedef unsigned long long u64t;

// ws layout (bytes):
//   [0, 262144)        hpk2[2][32][512] u64: {tag<<32 | (bf16hi | bf16lo<<16)}
//   [262144, +2MB)     Wh frags   [wg32][kb16][ct4][lane64][8] shorts
//   then Wl, Uh, Ul (2MB each).  total ~8.25 MB

__device__ inline unsigned short f2bf(float x){
    unsigned u = __float_as_uint(x);
    unsigned r = (u + 0x7fffu + ((u >> 16) & 1u)) >> 16;
    return (unsigned short)r;
}
__device__ inline float bf2f(unsigned short s){
    return __uint_as_float(((unsigned)s) << 16);
}

__global__ void prep_kernel(const float* __restrict__ W, const float* __restrict__ U,
                            const float* __restrict__ h0,
                            unsigned short* __restrict__ Wh, unsigned short* __restrict__ Wl,
                            unsigned short* __restrict__ Uh, unsigned short* __restrict__ Ul,
                            u64t* __restrict__ hpk2){
    int idx = blockIdx.x * blockDim.x + threadIdx.x;
    int stride = gridDim.x * blockDim.x;
    const int total = 2 * EDIM * 2048;  // 2^21
    for (int i = idx; i < total; i += stride){
        int mat = i >> 20;             // 0=W, 1=U
        int r = i & 1048575;
        int k = r >> 11;               // row in [0,512)
        int col = r & 2047;            // gate column in [0,2048)
        float v = (mat ? U : W)[(size_t)k * 2048 + col];
        unsigned short hi = f2bf(v);
        unsigned short lo = f2bf(v - bf2f(hi));
        int wg = (col & 511) >> 4;     // h-col block (16 cols per wg)
        int hc = col & 15;
        int g  = col >> 9;             // gate 0..3 == MFMA col-tile
        int kb = k >> 5;
        int kgrp = (k >> 3) & 3;
        int j = k & 7;
        size_t dst = (size_t)wg * 32768 + (size_t)kb * 2048 + (size_t)g * 512
                   + (size_t)(kgrp * 16 + hc) * 8 + j;
        if (mat){ Uh[dst] = hi; Ul[dst] = lo; } else { Wh[dst] = hi; Wl[dst] = lo; }
    }
    // h state buffers: buf0 = h0 with tag 0; buf1 = sentinel tag (never matches)
    for (int i = idx; i < BATCH * HDIM; i += stride){
        float v = h0[i];
        unsigned short hi = f2bf(v);
        unsigned short lo = f2bf(v - bf2f(hi));
        hpk2[i] = (u64t)((unsigned)hi | ((unsigned)lo << 16));          // tag 0
        hpk2[BATCH * HDIM + i] = 0xDEADBEEF00000000ULL;                  // sentinel
    }
}

__global__ __launch_bounds__(NTHR, 2) void lstm_scan(
        const float* __restrict__ src, const float* __restrict__ bias,
        const float* __restrict__ c0,
        const unsigned short* __restrict__ Wh, const unsigned short* __restrict__ Wl,
        const unsigned short* __restrict__ Uh, const unsigned short* __restrict__ Ul,
        u64t* __restrict__ hpk2,
        float* __restrict__ out){
    const int tid  = threadIdx.x;
    const int wg   = blockIdx.x;        // 0..31 -> h-cols [wg*16, wg*16+16)
    const int lane = tid & 63;
    const int w    = tid >> 6;          // wave 0..7
    const int bt   = w >> 2;            // batch tile (rows bt*16..)
    const int kq   = w & 3;             // K quarter (4 kb each)
    const int lc   = lane & 15;
    const int kgrp = lane >> 4;
    const int row  = bt * 16 + lc;      // batch index for A frags

    __shared__ float z_lds[4][BATCH][65];   // [kq][b][ct*16+hc], padded

    // gate cell: one per thread
    const int cb  = tid >> 4;      // batch 0..31
    const int chc = tid & 15;      // h-col within wg
    const int col = wg * 16 + chc;
    float c_state = c0[(size_t)cb * HDIM + col];
    float bias_g[4];
    #pragma unroll
    for (int g = 0; g < 4; g++) bias_g[g] = bias[g * HDIM + col];

    const uint4* WhF = reinterpret_cast<const uint4*>(Wh) + (size_t)wg * 4096;
    const uint4* WlF = reinterpret_cast<const uint4*>(Wl) + (size_t)wg * 4096;
    const uint4* UhF = reinterpret_cast<const uint4*>(Uh) + (size_t)wg * 4096;
    const uint4* UlF = reinterpret_cast<const uint4*>(Ul) + (size_t)wg * 4096;

    f32x4 acc[4];
    #pragma unroll
    for (int ct = 0; ct < 4; ct++)
        #pragma unroll
        for (int r = 0; r < 4; r++) acc[ct][r] = 0.f;

    // phase A: x_t @ W for this wave's (bt, kq), all 4 gate col-tiles
    auto phaseA = [&](int t){
        #pragma unroll
        for (int i = 0; i < 4; i++){
            int kb = kq * 4 + i;
            const float* xp = src + ((size_t)row * T_STEPS + t) * EDIM + kb * 32 + kgrp * 8;
            float xv[8];
            *reinterpret_cast<float4*>(&xv[0]) = *reinterpret_cast<const float4*>(xp);
            *reinterpret_cast<float4*>(&xv[4]) = *reinterpret_cast<const float4*>(xp + 4);
            bf16x8 ah, al;
            #pragma unroll
            for (int j = 0; j < 8; j++){
                unsigned short hi = f2bf(xv[j]);
                ah[j] = (short)hi;
                al[j] = (short)f2bf(xv[j] - bf2f(hi));
            }
            #pragma unroll
            for (int ct = 0; ct < 4; ct++){
                uint4 bh4 = WhF[kb * 256 + ct * 64 + lane];
                uint4 bl4 = WlF[kb * 256 + ct * 64 + lane];
                bf16x8 bh = *reinterpret_cast<bf16x8*>(&bh4);
                bf16x8 bl = *reinterpret_cast<bf16x8*>(&bl4);
                acc[ct] = __builtin_amdgcn_mfma_f32_16x16x32_bf16(ah, bh, acc[ct], 0, 0, 0);
                acc[ct] = __builtin_amdgcn_mfma_f32_16x16x32_bf16(ah, bl, acc[ct], 0, 0, 0);
                acc[ct] = __builtin_amdgcn_mfma_f32_16x16x32_bf16(al, bh, acc[ct], 0, 0, 0);
            }
        }
    };

    phaseA(0);

    for (int t = 0; t < T_STEPS; t++){
        // ---- poll + load h_t: self-tagged data, one L3 round trip ----
        const u64t* hp = hpk2 + (size_t)(t & 1) * (BATCH * HDIM) + (size_t)row * HDIM;
        u64t hv[4][8];
        {
            const unsigned tag = (unsigned)t;
            while (true){
                #pragma unroll
                for (int i = 0; i < 4; i++){
                    int base = (kq * 4 + i) * 32 + kgrp * 8;
                    #pragma unroll
                    for (int j = 0; j < 8; j++)
                        hv[i][j] = __hip_atomic_load(hp + base + j, __ATOMIC_RELAXED, __HIP_MEMORY_SCOPE_AGENT);
                }
                bool ok = true;
                #pragma unroll
                for (int i = 0; i < 4; i++)
                    #pragma unroll
                    for (int j = 0; j < 8; j++)
                        ok = ok && ((unsigned)(hv[i][j] >> 32) == tag);
                if (__all(ok)) break;
                __builtin_amdgcn_s_sleep(1);
            }
        }

        // ---- h_t @ U into acc ----
        #pragma unroll
        for (int i = 0; i < 4; i++){
            int kb = kq * 4 + i;
            bf16x8 ah, al;
            #pragma unroll
            for (int j = 0; j < 8; j++){
                unsigned p = (unsigned)hv[i][j];
                ah[j] = (short)(p & 0xffffu);
                al[j] = (short)(p >> 16);
            }
            #pragma unroll
            for (int ct = 0; ct < 4; ct++){
                uint4 uh4 = UhF[kb * 256 + ct * 64 + lane];
                uint4 ul4 = UlF[kb * 256 + ct * 64 + lane];
                bf16x8 uh = *reinterpret_cast<bf16x8*>(&uh4);
                bf16x8 ul = *reinterpret_cast<bf16x8*>(&ul4);
                acc[ct] = __builtin_amdgcn_mfma_f32_16x16x32_bf16(ah, uh, acc[ct], 0, 0, 0);
                acc[ct] = __builtin_amdgcn_mfma_f32_16x16x32_bf16(ah, ul, acc[ct], 0, 0, 0);
                acc[ct] = __builtin_amdgcn_mfma_f32_16x16x32_bf16(al, uh, acc[ct], 0, 0, 0);
            }
        }

        // ---- exchange partial z through LDS ----
        #pragma unroll
        for (int ct = 0; ct < 4; ct++)
            #pragma unroll
            for (int r = 0; r < 4; r++)
                z_lds[kq][bt * 16 + kgrp * 4 + r][ct * 16 + lc] = acc[ct][r];
        __syncthreads();

        // ---- gates: all 512 threads, one cell (cb, chc) each ----
        {
            float z[4];
            #pragma unroll
            for (int g = 0; g < 4; g++)
                z[g] = z_lds[0][cb][g * 16 + chc] + z_lds[1][cb][g * 16 + chc]
                     + z_lds[2][cb][g * 16 + chc] + z_lds[3][cb][g * 16 + chc] + bias_g[g];
            float ig = 1.f / (1.f + __expf(-z[0]));
            float fg = 1.f / (1.f + __expf(-z[1]));
            float gg = tanhf(z[2]);
            float og = 1.f / (1.f + __expf(-z[3]));
            float cn = fg * c_state + ig * gg;
            c_state = cn;
            float hn = og * tanhf(cn);
            out[16384 + ((size_t)t * BATCH + cb) * HDIM + col] = hn;   // hs[t][b][col]
            if (t == T_STEPS - 1){
                out[(size_t)cb * HDIM + col] = hn;                                          // h_T (out 0)
                out[16384 + (size_t)T_STEPS * BATCH * HDIM + (size_t)cb * HDIM + col] = hn; // h_T (out 2)
            }
            unsigned short hi = f2bf(hn);
            unsigned short lo = f2bf(hn - bf2f(hi));
            u64t pv = ((u64t)(unsigned)(t + 1) << 32)
                    | (u64t)((unsigned)hi | ((unsigned)lo << 16));
            // self-tagged write-through store: the message IS the sync
            __hip_atomic_store(&hpk2[(size_t)((t + 1) & 1) * (BATCH * HDIM) + (size_t)cb * HDIM + col],
                               pv, __ATOMIC_RELAXED, __HIP_MEMORY_SCOPE_AGENT);
        }
        __syncthreads();   // protect z_lds before next step's overwrite

        // ---- phase A for t+1 (overlaps other WGs' h propagation) ----
        #pragma unroll
        for (int ct = 0; ct < 4; ct++)
            #pragma unroll
            for (int r = 0; r < 4; r++) acc[ct][r] = 0.f;
        if (t + 1 < T_STEPS) phaseA(t + 1);
    }
}

extern "C" void kernel_launch(void* const* d_in, const int* in_sizes, int n_in,
                              void* d_out, int out_size, void* d_ws, size_t ws_size,
                              hipStream_t stream){
    const float* src = (const float*)d_in[0];
    const float* W   = (const float*)d_in[1];
    const float* U   = (const float*)d_in[2];
    const float* b   = (const float*)d_in[3];
    const float* h0  = (const float*)d_in[4];
    const float* c0  = (const float*)d_in[5];
    float* out = (float*)d_out;

    char* ws = (char*)d_ws;
    u64t*           hpk2 = (u64t*)(ws);
    unsigned short* Wh   = (unsigned short*)(ws + 262144);
    unsigned short* Wl   = Wh + 1048576;
    unsigned short* Uh   = Wl + 1048576;
    unsigned short* Ul   = Uh + 1048576;

    prep_kernel<<<1024, 256, 0, stream>>>(W, U, h0, Wh, Wl, Uh, Ul, hpk2);
    lstm_scan<<<NWG, NTHR, 0, stream>>>(src, b, c0, Wh, Wl, Uh, Ul, hpk2, out);
}

// Round 4
// 24678.720 us; speedup vs baseline: 1.1641x; 1.1641x over previous
//
#include <hip/hip_runtime.h>
#include <stdint.h>

#define T_STEPS 2048
#define BATCH 32
#define EDIM 512
#define HDIM 512
#define NWG 32
#define NTHR 512

typedef __attribute__((ext_vector_type(8))) short bf16x8;
typedef __attribute__((ext_vector_type(4))) float f32x4;
typedef unsigned long long u64t;

// ws layout (bytes):
//   [0, 262144)        hpkT[2][512][32] u64: {tag<<32 | (bf16hi | bf16lo<<16)}, k-major
//   [262144, +2MB)     Wh frags [wg32][kb16][ct4][lane64][8] shorts
//   then Wl, Uh, Ul (2MB each).  total ~8.25 MB

__device__ inline unsigned short f2bf(float x){
    unsigned u = __float_as_uint(x);
    unsigned r = (u + 0x7fffu + ((u >> 16) & 1u)) >> 16;
    return (unsigned short)r;
}
__device__ inline float bf2f(unsigned short s){
    return __uint_as_float(((unsigned)s) << 16);
}

__global__ void prep_kernel(const float* __restrict__ W, const float* __restrict__ U,
                            const float* __restrict__ h0,
                            unsigned short* __restrict__ Wh, unsigned short* __restrict__ Wl,
                            unsigned short* __restrict__ Uh, unsigned short* __restrict__ Ul,
                            u64t* __restrict__ hpkT){
    int idx = blockIdx.x * blockDim.x + threadIdx.x;
    int stride = gridDim.x * blockDim.x;
    const int total = 2 * EDIM * 2048;  // 2^21
    for (int i = idx; i < total; i += stride){
        int mat = i >> 20;             // 0=W, 1=U
        int r = i & 1048575;
        int k = r >> 11;               // row in [0,512)
        int col = r & 2047;            // gate column in [0,2048)
        float v = (mat ? U : W)[(size_t)k * 2048 + col];
        unsigned short hi = f2bf(v);
        unsigned short lo = f2bf(v - bf2f(hi));
        int wg = (col & 511) >> 4;     // h-col block (16 cols per wg)
        int hc = col & 15;
        int g  = col >> 9;             // gate 0..3 == MFMA col-tile
        int kb = k >> 5;
        int kgrp = (k >> 3) & 3;
        int j = k & 7;
        size_t dst = (size_t)wg * 32768 + (size_t)kb * 2048 + (size_t)g * 512
                   + (size_t)(kgrp * 16 + hc) * 8 + j;
        if (mat){ Uh[dst] = hi; Ul[dst] = lo; } else { Wh[dst] = hi; Wl[dst] = lo; }
    }
    // h state buffers (transposed, tagged): buf0 = {tag0, h0}; buf1 = sentinel
    for (int i = idx; i < BATCH * HDIM; i += stride){
        int b = i >> 9;                // h0 is [B][H]
        int k = i & 511;
        float v = h0[i];
        unsigned short hi = f2bf(v);
        unsigned short lo = f2bf(v - bf2f(hi));
        hpkT[(size_t)k * 32 + b] = (u64t)((unsigned)hi | ((unsigned)lo << 16));  // tag 0
        hpkT[16384 + (size_t)k * 32 + b] = 0x8000000000000000ULL;                // sentinel
    }
}

__global__ __launch_bounds__(NTHR, 2) void lstm_scan(
        const float* __restrict__ src, const float* __restrict__ bias,
        const float* __restrict__ c0,
        const unsigned short* __restrict__ Wh, const unsigned short* __restrict__ Wl,
        const unsigned short* __restrict__ Uh, const unsigned short* __restrict__ Ul,
        u64t* __restrict__ hpkT,
        float* __restrict__ out){
    const int tid  = threadIdx.x;
    const int wg   = blockIdx.x;        // 0..31 -> h-cols [wg*16, wg*16+16)
    const int lane = tid & 63;
    const int w    = tid >> 6;          // wave 0..7
    const int bt   = w >> 2;            // batch tile (rows bt*16..)
    const int kq   = w & 3;             // K quarter (128 k-values)
    const int lc   = lane & 15;
    const int kgrp = lane >> 4;
    const int row  = bt * 16 + lc;      // batch index for A frags (phase A)

    __shared__ unsigned int hlds[8][128][17];   // per-wave h tile, padded (69632 B)
    __shared__ float z_lds[4][BATCH][65];       // [kq][b][ct*16+hc]   (33280 B)

    // gate cell: one per thread
    const int cb  = tid >> 4;      // batch 0..31
    const int chc = tid & 15;      // h-col within wg
    const int col = wg * 16 + chc;
    float c_state = c0[(size_t)cb * HDIM + col];
    float bias_g[4];
    #pragma unroll
    for (int g = 0; g < 4; g++) bias_g[g] = bias[g * HDIM + col];

    const uint4* WhF = reinterpret_cast<const uint4*>(Wh) + (size_t)wg * 4096;
    const uint4* WlF = reinterpret_cast<const uint4*>(Wl) + (size_t)wg * 4096;
    const uint4* UhF = reinterpret_cast<const uint4*>(Uh) + (size_t)wg * 4096;
    const uint4* UlF = reinterpret_cast<const uint4*>(Ul) + (size_t)wg * 4096;

    f32x4 acc[4];
    #pragma unroll
    for (int ct = 0; ct < 4; ct++)
        #pragma unroll
        for (int r = 0; r < 4; r++) acc[ct][r] = 0.f;

    // phase A: x_t @ W for this wave's (bt, kq), all 4 gate col-tiles
    auto phaseA = [&](int t){
        #pragma unroll
        for (int i = 0; i < 4; i++){
            int kb = kq * 4 + i;
            const float* xp = src + ((size_t)row * T_STEPS + t) * EDIM + kb * 32 + kgrp * 8;
            float xv[8];
            *reinterpret_cast<float4*>(&xv[0]) = *reinterpret_cast<const float4*>(xp);
            *reinterpret_cast<float4*>(&xv[4]) = *reinterpret_cast<const float4*>(xp + 4);
            bf16x8 ah, al;
            #pragma unroll
            for (int j = 0; j < 8; j++){
                unsigned short hi = f2bf(xv[j]);
                ah[j] = (short)hi;
                al[j] = (short)f2bf(xv[j] - bf2f(hi));
            }
            #pragma unroll
            for (int ct = 0; ct < 4; ct++){
                uint4 bh4 = WhF[kb * 256 + ct * 64 + lane];
                uint4 bl4 = WlF[kb * 256 + ct * 64 + lane];
                bf16x8 bh = *reinterpret_cast<bf16x8*>(&bh4);
                bf16x8 bl = *reinterpret_cast<bf16x8*>(&bl4);
                acc[ct] = __builtin_amdgcn_mfma_f32_16x16x32_bf16(ah, bh, acc[ct], 0, 0, 0);
                acc[ct] = __builtin_amdgcn_mfma_f32_16x16x32_bf16(ah, bl, acc[ct], 0, 0, 0);
                acc[ct] = __builtin_amdgcn_mfma_f32_16x16x32_bf16(al, bh, acc[ct], 0, 0, 0);
            }
        }
    };

    phaseA(0);

    for (int t = 0; t < T_STEPS; t++){
        // ---- poll + load h_t: coalesced self-tagged tile (128k x 16b u64) ----
        const u64t* hp = hpkT + (size_t)(t & 1) * 16384 + (size_t)(kq * 128) * 32 + bt * 16;
        u64t hv[32];
        {
            const unsigned tag = (unsigned)t;
            while (true){
                #pragma unroll
                for (int m = 0; m < 32; m++){
                    int c = m * 64 + lane;       // fixed m: 4 k-rows x 16 b -> 8 dense lines
                    hv[m] = __hip_atomic_load(hp + (size_t)(c >> 4) * 32 + (c & 15),
                                              __ATOMIC_RELAXED, __HIP_MEMORY_SCOPE_AGENT);
                }
                bool ok = true;
                #pragma unroll
                for (int m = 0; m < 32; m++)
                    ok = ok && ((unsigned)(hv[m] >> 32) == tag);
                if (__all(ok)) break;
                __builtin_amdgcn_s_sleep(2);
            }
        }
        // route through wave-private LDS to fragment layout
        #pragma unroll
        for (int m = 0; m < 32; m++){
            int c = m * 64 + lane;
            hlds[w][c >> 4][c & 15] = (unsigned)hv[m];
        }
        __syncthreads();   // B1: hlds visible to own wave; also fences z_lds reuse

        // ---- h_t @ U into acc ----
        #pragma unroll
        for (int i = 0; i < 4; i++){
            int kb = kq * 4 + i;
            bf16x8 ah, al;
            #pragma unroll
            for (int j = 0; j < 8; j++){
                unsigned p = hlds[w][i * 32 + kgrp * 8 + j][lc];
                ah[j] = (short)(p & 0xffffu);
                al[j] = (short)(p >> 16);
            }
            #pragma unroll
            for (int ct = 0; ct < 4; ct++){
                uint4 uh4 = UhF[kb * 256 + ct * 64 + lane];
                uint4 ul4 = UlF[kb * 256 + ct * 64 + lane];
                bf16x8 uh = *reinterpret_cast<bf16x8*>(&uh4);
                bf16x8 ul = *reinterpret_cast<bf16x8*>(&ul4);
                acc[ct] = __builtin_amdgcn_mfma_f32_16x16x32_bf16(ah, uh, acc[ct], 0, 0, 0);
                acc[ct] = __builtin_amdgcn_mfma_f32_16x16x32_bf16(ah, ul, acc[ct], 0, 0, 0);
                acc[ct] = __builtin_amdgcn_mfma_f32_16x16x32_bf16(al, uh, acc[ct], 0, 0, 0);
            }
        }

        // ---- exchange partial z through LDS ----
        #pragma unroll
        for (int ct = 0; ct < 4; ct++)
            #pragma unroll
            for (int r = 0; r < 4; r++)
                z_lds[kq][bt * 16 + kgrp * 4 + r][ct * 16 + lc] = acc[ct][r];
        __syncthreads();   // B2

        // ---- gates: all 512 threads, one cell (cb, chc) each ----
        {
            float z[4];
            #pragma unroll
            for (int g = 0; g < 4; g++)
                z[g] = z_lds[0][cb][g * 16 + chc] + z_lds[1][cb][g * 16 + chc]
                     + z_lds[2][cb][g * 16 + chc] + z_lds[3][cb][g * 16 + chc] + bias_g[g];
            float ig = 1.f / (1.f + __expf(-z[0]));
            float fg = 1.f / (1.f + __expf(-z[1]));
            float gg = tanhf(z[2]);
            float og = 1.f / (1.f + __expf(-z[3]));
            float cn = fg * c_state + ig * gg;
            c_state = cn;
            float hn = og * tanhf(cn);
            out[16384 + ((size_t)t * BATCH + cb) * HDIM + col] = hn;   // hs[t][b][col]
            if (t == T_STEPS - 1){
                out[(size_t)cb * HDIM + col] = hn;                                          // h_T (out 0)
                out[16384 + (size_t)T_STEPS * BATCH * HDIM + (size_t)cb * HDIM + col] = hn; // h_T (out 2)
            }
            unsigned short hi = f2bf(hn);
            unsigned short lo = f2bf(hn - bf2f(hi));
            u64t pv = ((u64t)(unsigned)(t + 1) << 32)
                    | (u64t)((unsigned)hi | ((unsigned)lo << 16));
            // self-tagged write-through store to transposed layout: message IS the sync
            __hip_atomic_store(&hpkT[(size_t)((t + 1) & 1) * 16384 + (size_t)col * 32 + cb],
                               pv, __ATOMIC_RELAXED, __HIP_MEMORY_SCOPE_AGENT);
        }

        // ---- phase A for t+1 (overlaps the h broadcast) ----
        #pragma unroll
        for (int ct = 0; ct < 4; ct++)
            #pragma unroll
            for (int r = 0; r < 4; r++) acc[ct][r] = 0.f;
        if (t + 1 < T_STEPS) phaseA(t + 1);
    }
}

extern "C" void kernel_launch(void* const* d_in, const int* in_sizes, int n_in,
                              void* d_out, int out_size, void* d_ws, size_t ws_size,
                              hipStream_t stream){
    const float* src = (const float*)d_in[0];
    const float* W   = (const float*)d_in[1];
    const float* U   = (const float*)d_in[2];
    const float* b   = (const float*)d_in[3];
    const float* h0  = (const float*)d_in[4];
    const float* c0  = (const float*)d_in[5];
    float* out = (float*)d_out;

    char* ws = (char*)d_ws;
    u64t*           hpkT = (u64t*)(ws);
    unsigned short* Wh   = (unsigned short*)(ws + 262144);
    unsigned short* Wl   = Wh + 1048576;
    unsigned short* Uh   = Wl + 1048576;
    unsigned short* Ul   = Uh + 1048576;

    prep_kernel<<<1024, 256, 0, stream>>>(W, U, h0, Wh, Wl, Uh, Ul, hpkT);
    lstm_scan<<<NWG, NTHR, 0, stream>>>(src, b, c0, Wh, Wl, Uh, Ul, hpkT, out);
}